// Round 1
// baseline (1083.168 us; speedup 1.0000x reference)
//
#include <hip/hip_runtime.h>
#include <hip/hip_bf16.h>

#define EPS 1e-6f
#define H 512
#define W 512
#define NB 8
#define NC 8
#define NS 7

__device__ __forceinline__ int refl(int t, int n) {
    if (t < 0) t = -t;
    if (t >= n) t = 2 * n - 2 - t;
    return t;
}

__device__ __forceinline__ float tanh_fast(float x) {
    // tanh(x) = 1 - 2/(exp(2x)+1); saturates correctly for large |x|
    return 1.f - 2.f / (__expf(2.f * x) + 1.f);
}

// Kernel A: u_sigma = reflect-pad 5x5 gaussian conv of est; per-image max via atomicMax
__global__ __launch_bounds__(256) void gauss_max_kernel(
    const float* __restrict__ est, const float* __restrict__ gauss,
    float* __restrict__ usig, unsigned* __restrict__ gmax)
{
    __shared__ float gk[25];
    const int tx = threadIdx.x, ty = threadIdx.y;
    const int tid = ty * 64 + tx;
    const int x = blockIdx.x * 64 + tx;
    const int y = blockIdx.y * 4 + ty;
    const int b = blockIdx.z;
    const float* e = est + (size_t)b * H * W;

    if (tid < 25) gk[tid] = gauss[tid];
    __syncthreads();

    int yy[5], xx[5];
#pragma unroll
    for (int i = 0; i < 5; i++) { yy[i] = refl(y + i - 2, H); xx[i] = refl(x + i - 2, W); }

    float acc = 0.f;
#pragma unroll
    for (int i = 0; i < 5; i++) {
#pragma unroll
        for (int j = 0; j < 5; j++)
            acc += e[yy[i] * W + xx[j]] * gk[i * 5 + j];
    }
    usig[(size_t)b * H * W + y * W + x] = acc;

    // block max reduce (wave64 shfl then LDS across the 4 waves)
    float m = acc;
#pragma unroll
    for (int off = 32; off > 0; off >>= 1)
        m = fmaxf(m, __shfl_down(m, off, 64));
    __shared__ float wm[4];
    if ((tid & 63) == 0) wm[tid >> 6] = m;
    __syncthreads();
    if (tid == 0) {
        float mm = fmaxf(fmaxf(wm[0], wm[1]), fmaxf(wm[2], wm[3]));
        atomicMax(gmax + b, __float_as_uint(mm));  // all values > 0: uint order == float order
    }
}

// Kernel B: one full stage update for a 16x16 tile.
#define TS 16
__global__ __launch_bounds__(256) void stage_kernel(
    const float* __restrict__ est, const float* __restrict__ noisy,
    const float* __restrict__ usig, const unsigned* __restrict__ gmax,
    const float* __restrict__ filt,  // [8][9] for this stage
    const float* __restrict__ wv, const float* __restrict__ bv,
    const float* __restrict__ lamp, const float* __restrict__ gatep,
    float* __restrict__ out)
{
    __shared__ float esh[20][20];        // est tile + halo 2 (reflect)
    __shared__ float ush[18][18];        // u_sigma tile + halo 1
    __shared__ float zsh[NC][18][18];    // z tile + halo 1 (zero outside image)
    __shared__ float fsh[NC][9];
    __shared__ float wsh[NC], bsh[NC];

    const int tx = threadIdx.x, ty = threadIdx.y;
    const int tid = ty * TS + tx;
    const int tx0 = blockIdx.x * TS, ty0 = blockIdx.y * TS;
    const int b = blockIdx.z;
    const float* e  = est   + (size_t)b * H * W;
    const float* nz = noisy + (size_t)b * H * W;
    const float* us = usig  + (size_t)b * H * W;

    if (tid < 72) fsh[tid / 9][tid % 9] = filt[tid];
    else if (tid < 80) { wsh[tid - 72] = wv[tid - 72]; bsh[tid - 72] = bv[tid - 72]; }

    const float lam = lamp[0];
    const float g = 1.f / (1.f + __expf(-gatep[0]));
    const float dinv = 1.f / fmaxf(__uint_as_float(gmax[b]), EPS);

    for (int i = tid; i < 400; i += 256) {
        int ly = i / 20, lx = i % 20;
        esh[ly][lx] = e[refl(ty0 + ly - 2, H) * W + refl(tx0 + lx - 2, W)];
    }
    for (int i = tid; i < 324; i += 256) {
        int ly = i / 18, lx = i % 18;
        int gy = ty0 + ly - 1, gx = tx0 + lx - 1;
        ush[ly][lx] = (gy >= 0 && gy < H && gx >= 0 && gx < W) ? us[gy * W + gx] : 0.f;
    }
    __syncthreads();

    // z over the 18x18 region (zero outside the image: zero-pad transpose conv)
    for (int i = tid; i < 324; i += 256) {
        int ly = i / 18, lx = i % 18;
        int gy = ty0 + ly - 1, gx = tx0 + lx - 1;
        bool valid = (gy >= 0 && gy < H && gx >= 0 && gx < W);
        float iw = fmaxf(ush[ly][lx] * dinv, EPS);
        float ew[9];
#pragma unroll
        for (int dy = 0; dy < 3; dy++)
#pragma unroll
            for (int dx = 0; dx < 3; dx++)
                ew[dy * 3 + dx] = esh[ly + dy][lx + dx];
#pragma unroll
        for (int c = 0; c < NC; c++) {
            float r = 0.f;
#pragma unroll
            for (int k = 0; k < 9; k++) r += ew[k] * fsh[c][k];
            float t = tanh_fast(r * wsh[c] + bsh[c]);
            zsh[c][ly][lx] = valid ? iw * t : 0.f;
        }
    }
    __syncthreads();

    // synthesis conv (channel sum, zero pad) + pointwise update
    const int y = ty0 + ty, x = tx0 + tx;
    float diff = 0.f;
#pragma unroll
    for (int c = 0; c < NC; c++)
#pragma unroll
        for (int ky = 0; ky < 3; ky++)
#pragma unroll
            for (int kx = 0; kx < 3; kx++)
                diff += zsh[c][ty + ky][tx + kx] * fsh[c][ky * 3 + kx];

    float eo = esh[ty + 2][tx + 2];
    float n0 = nz[y * W + x];
    float iwc = fmaxf(ush[ty + 1][tx + 1] * dinv, EPS);
    float fg = (eo - n0) / (eo * eo + EPS);
    float est2 = eo - diff - lam * iwc * fg;
    float en = est2 + g * (n0 - est2);
    en = fminf(fmaxf(en, EPS), 1.f);
    out[(size_t)b * H * W + y * W + x] = en;
}

extern "C" void kernel_launch(void* const* d_in, const int* in_sizes, int n_in,
                              void* d_out, int out_size, void* d_ws, size_t ws_size,
                              hipStream_t stream)
{
    const float* noisy   = (const float*)d_in[0];
    const float* filters = (const float*)d_in[1];  // [7][8][1][3][3]
    const float* wv      = (const float*)d_in[2];  // [7][8]
    const float* bv      = (const float*)d_in[3];  // [7][8]
    const float* lam     = (const float*)d_in[4];  // [7]
    const float* gate    = (const float*)d_in[5];  // [7]
    const float* gauss   = (const float*)d_in[6];  // [25]
    float* out = (float*)d_out;

    char* ws = (char*)d_ws;
    float* ws0      = (float*)ws;                    // 8 MB ping buffer
    float* usig     = (float*)(ws + (8u << 20));     // 8 MB u_sigma
    unsigned* gmax  = (unsigned*)(ws + (16u << 20)); // 7*8 per-stage per-image maxes

    hipMemsetAsync(gmax, 0, NS * NB * sizeof(unsigned), stream);

    const float* cur = noisy;
    for (int s = 0; s < NS; s++) {
        float* nxt = (s % 2 == 0) ? out : ws0;  // odd count of stages -> final lands in out
        gauss_max_kernel<<<dim3(W / 64, H / 4, NB), dim3(64, 4), 0, stream>>>(
            cur, gauss, usig, gmax + s * NB);
        stage_kernel<<<dim3(W / TS, H / TS, NB), dim3(TS, TS), 0, stream>>>(
            cur, noisy, usig, gmax + s * NB,
            filters + s * NC * 9, wv + s * NC, bv + s * NC, lam + s, gate + s, nxt);
        cur = nxt;
    }
}

// Round 2
// 484.155 us; speedup vs baseline: 2.2372x; 2.2372x over previous
//
#include <hip/hip_runtime.h>
#include <hip/hip_bf16.h>

#define EPS 1e-6f
#define H 512
#define W 512
#define NB 8
#define NC 8
#define NS 7

// gauss tile geometry: 64 wide x 32 tall per block, 128 blocks per image
#define GTX 64
#define GTY 32
#define NBLK 128

__device__ __forceinline__ int refl(int t, int n) {
    if (t < 0) t = -t;
    if (t >= n) t = 2 * n - 2 - t;
    return t;
}

__device__ __forceinline__ float tanh_fast(float x) {
    return 1.f - 2.f / (__expf(2.f * x) + 1.f);
}

// Kernel A: separable 5x5 gaussian (reflect pad) + per-block max -> blockmax slot.
// No atomics: each block owns one slot.
__global__ __launch_bounds__(256) void gauss_sep_kernel(
    const float* __restrict__ est, const float* __restrict__ gauss,
    float* __restrict__ usig, float* __restrict__ blockmax)
{
    __shared__ float hbuf[GTY + 4][GTX];   // horizontal-pass result, 9216 B
    __shared__ float wm[4];

    const int tx = threadIdx.x, ty = threadIdx.y;   // block (64,4)
    const int x0 = blockIdx.x * GTX, y0 = blockIdx.y * GTY;
    const int b = blockIdx.z;
    const float* e = est + (size_t)b * H * W;

    // exact separable decomposition: k2d = outer(g1,g1), so g1[i] = sqrt(k2d[i][i])
    const float g0 = sqrtf(gauss[0]);    // == g4
    const float g1 = sqrtf(gauss[6]);    // == g3
    const float g2 = sqrtf(gauss[12]);

    int xx[5];
#pragma unroll
    for (int j = 0; j < 5; j++) xx[j] = refl(x0 + tx + j - 2, W);

    // horizontal pass over GTY+4 rows (reflect in y), coalesced row reads
    for (int r = ty; r < GTY + 4; r += 4) {
        const float* row = e + refl(y0 + r - 2, H) * W;
        hbuf[r][tx] = g0 * (row[xx[0]] + row[xx[4]])
                    + g1 * (row[xx[1]] + row[xx[3]])
                    + g2 * row[xx[2]];
    }
    __syncthreads();

    // vertical pass: each thread does 8 consecutive rows at column tx (rolling window)
    const int r0 = ty * 8;
    float v0 = hbuf[r0 + 0][tx];
    float v1 = hbuf[r0 + 1][tx];
    float v2 = hbuf[r0 + 2][tx];
    float v3 = hbuf[r0 + 3][tx];
    float m = 0.f;
    float* orow = usig + (size_t)b * H * W + (size_t)(y0 + r0) * W + x0 + tx;
#pragma unroll
    for (int rr = 0; rr < 8; rr++) {
        float v4 = hbuf[r0 + rr + 4][tx];
        float o = g0 * (v0 + v4) + g1 * (v1 + v3) + g2 * v2;
        orow[(size_t)rr * W] = o;
        m = fmaxf(m, o);
        v0 = v1; v1 = v2; v2 = v3; v3 = v4;
    }

    // block max: wave reduce (each wave is one ty row), then 4-way combine
#pragma unroll
    for (int off = 32; off > 0; off >>= 1)
        m = fmaxf(m, __shfl_xor(m, off, 64));
    if (tx == 0) wm[ty] = m;
    __syncthreads();
    if (tx == 0 && ty == 0) {
        float mm = fmaxf(fmaxf(wm[0], wm[1]), fmaxf(wm[2], wm[3]));
        blockmax[b * NBLK + blockIdx.y * gridDim.x + blockIdx.x] = mm;
    }
}

// Kernel B: one full stage update for a 16x16 tile.
#define TS 16
__global__ __launch_bounds__(256) void stage_kernel(
    const float* __restrict__ est, const float* __restrict__ noisy,
    const float* __restrict__ usig, const float* __restrict__ blockmax,
    const float* __restrict__ filt,  // [8][9] for this stage
    const float* __restrict__ wv, const float* __restrict__ bv,
    const float* __restrict__ lamp, const float* __restrict__ gatep,
    float* __restrict__ out)
{
    __shared__ float esh[20][20];        // est tile + halo 2 (reflect)
    __shared__ float ush[18][18];        // u_sigma tile + halo 1
    __shared__ float zsh[NC][18][18];    // z tile + halo 1 (zero outside image)
    __shared__ float fsh[NC][9];
    __shared__ float wsh[NC], bsh[NC];

    const int tx = threadIdx.x, ty = threadIdx.y;
    const int tid = ty * TS + tx;
    const int tx0 = blockIdx.x * TS, ty0 = blockIdx.y * TS;
    const int b = blockIdx.z;
    const float* e  = est   + (size_t)b * H * W;
    const float* nz = noisy + (size_t)b * H * W;
    const float* us = usig  + (size_t)b * H * W;

    if (tid < 72) fsh[tid / 9][tid % 9] = filt[tid];
    else if (tid < 80) { wsh[tid - 72] = wv[tid - 72]; bsh[tid - 72] = bv[tid - 72]; }

    // per-wave reduction of the 128 per-block maxes for this image (no atomics)
    float m = fmaxf(blockmax[b * NBLK + (tid & 63)],
                    blockmax[b * NBLK + 64 + (tid & 63)]);
#pragma unroll
    for (int off = 32; off > 0; off >>= 1)
        m = fmaxf(m, __shfl_xor(m, off, 64));
    const float dinv = 1.f / fmaxf(m, EPS);

    const float lam = lamp[0];
    const float g = 1.f / (1.f + __expf(-gatep[0]));

    for (int i = tid; i < 400; i += 256) {
        int ly = i / 20, lx = i % 20;
        esh[ly][lx] = e[refl(ty0 + ly - 2, H) * W + refl(tx0 + lx - 2, W)];
    }
    for (int i = tid; i < 324; i += 256) {
        int ly = i / 18, lx = i % 18;
        int gy = ty0 + ly - 1, gx = tx0 + lx - 1;
        ush[ly][lx] = (gy >= 0 && gy < H && gx >= 0 && gx < W) ? us[gy * W + gx] : 0.f;
    }
    __syncthreads();

    // z over the 18x18 region (zero outside the image: zero-pad transpose conv)
    for (int i = tid; i < 324; i += 256) {
        int ly = i / 18, lx = i % 18;
        int gy = ty0 + ly - 1, gx = tx0 + lx - 1;
        bool valid = (gy >= 0 && gy < H && gx >= 0 && gx < W);
        float iw = fmaxf(ush[ly][lx] * dinv, EPS);
        float ew[9];
#pragma unroll
        for (int dy = 0; dy < 3; dy++)
#pragma unroll
            for (int dx = 0; dx < 3; dx++)
                ew[dy * 3 + dx] = esh[ly + dy][lx + dx];
#pragma unroll
        for (int c = 0; c < NC; c++) {
            float r = 0.f;
#pragma unroll
            for (int k = 0; k < 9; k++) r += ew[k] * fsh[c][k];
            float t = tanh_fast(r * wsh[c] + bsh[c]);
            zsh[c][ly][lx] = valid ? iw * t : 0.f;
        }
    }
    __syncthreads();

    // synthesis conv (channel sum, zero pad) + pointwise update
    const int y = ty0 + ty, x = tx0 + tx;
    float diff = 0.f;
#pragma unroll
    for (int c = 0; c < NC; c++)
#pragma unroll
        for (int ky = 0; ky < 3; ky++)
#pragma unroll
            for (int kx = 0; kx < 3; kx++)
                diff += zsh[c][ty + ky][tx + kx] * fsh[c][ky * 3 + kx];

    float eo = esh[ty + 2][tx + 2];
    float n0 = nz[y * W + x];
    float iwc = fmaxf(ush[ty + 1][tx + 1] * dinv, EPS);
    float fg = (eo - n0) / (eo * eo + EPS);
    float est2 = eo - diff - lam * iwc * fg;
    float en = est2 + g * (n0 - est2);
    en = fminf(fmaxf(en, EPS), 1.f);
    out[(size_t)b * H * W + y * W + x] = en;
}

extern "C" void kernel_launch(void* const* d_in, const int* in_sizes, int n_in,
                              void* d_out, int out_size, void* d_ws, size_t ws_size,
                              hipStream_t stream)
{
    const float* noisy   = (const float*)d_in[0];
    const float* filters = (const float*)d_in[1];  // [7][8][1][3][3]
    const float* wv      = (const float*)d_in[2];  // [7][8]
    const float* bv      = (const float*)d_in[3];  // [7][8]
    const float* lam     = (const float*)d_in[4];  // [7]
    const float* gate    = (const float*)d_in[5];  // [7]
    const float* gauss   = (const float*)d_in[6];  // [25]
    float* out = (float*)d_out;

    char* ws = (char*)d_ws;
    float* ws0      = (float*)ws;                    // 8 MB ping buffer
    float* usig     = (float*)(ws + (8u << 20));     // 8 MB u_sigma
    float* blockmax = (float*)(ws + (16u << 20));    // 128*8 floats, rewritten each stage

    const float* cur = noisy;
    for (int s = 0; s < NS; s++) {
        float* nxt = (s % 2 == 0) ? out : ws0;  // odd stage count -> final lands in out
        gauss_sep_kernel<<<dim3(W / GTX, H / GTY, NB), dim3(64, 4), 0, stream>>>(
            cur, gauss, usig, blockmax);
        stage_kernel<<<dim3(W / TS, H / TS, NB), dim3(TS, TS), 0, stream>>>(
            cur, noisy, usig, blockmax,
            filters + s * NC * 9, wv + s * NC, bv + s * NC, lam + s, gate + s, nxt);
        cur = nxt;
    }
}

// Round 3
// 330.764 us; speedup vs baseline: 3.2747x; 1.4637x over previous
//
#include <hip/hip_runtime.h>
#include <hip/hip_bf16.h>

#define EPS 1e-6f
#define H 512
#define W 512
#define NB 8
#define NC 8
#define NS 7
#define LOG2E 1.4426950408889634f

// gauss tile geometry: 64 wide x 32 tall per block, 128 blocks per image
#define GTX 64
#define GTY 32
#define NBLK 128

__device__ __forceinline__ int refl(int t, int n) {
    if (t < 0) t = -t;
    if (t >= n) t = 2 * n - 2 - t;
    return t;
}

// Kernel A: separable 5x5 gaussian (reflect pad) + per-block max -> blockmax slot.
__global__ __launch_bounds__(256) void gauss_sep_kernel(
    const float* __restrict__ est, const float* __restrict__ gauss,
    float* __restrict__ usig, float* __restrict__ blockmax)
{
    __shared__ float hbuf[GTY + 4][GTX];
    __shared__ float wm[4];

    const int tx = threadIdx.x, ty = threadIdx.y;   // block (64,4)
    const int x0 = blockIdx.x * GTX, y0 = blockIdx.y * GTY;
    const int b = blockIdx.z;
    const float* e = est + (size_t)b * H * W;

    const float g0 = sqrtf(gauss[0]);
    const float g1 = sqrtf(gauss[6]);
    const float g2 = sqrtf(gauss[12]);

    int xx[5];
#pragma unroll
    for (int j = 0; j < 5; j++) xx[j] = refl(x0 + tx + j - 2, W);

    for (int r = ty; r < GTY + 4; r += 4) {
        const float* row = e + refl(y0 + r - 2, H) * W;
        hbuf[r][tx] = g0 * (row[xx[0]] + row[xx[4]])
                    + g1 * (row[xx[1]] + row[xx[3]])
                    + g2 * row[xx[2]];
    }
    __syncthreads();

    const int r0 = ty * 8;
    float v0 = hbuf[r0 + 0][tx];
    float v1 = hbuf[r0 + 1][tx];
    float v2 = hbuf[r0 + 2][tx];
    float v3 = hbuf[r0 + 3][tx];
    float m = 0.f;
    float* orow = usig + (size_t)b * H * W + (size_t)(y0 + r0) * W + x0 + tx;
#pragma unroll
    for (int rr = 0; rr < 8; rr++) {
        float v4 = hbuf[r0 + rr + 4][tx];
        float o = g0 * (v0 + v4) + g1 * (v1 + v3) + g2 * v2;
        orow[(size_t)rr * W] = o;
        m = fmaxf(m, o);
        v0 = v1; v1 = v2; v2 = v3; v3 = v4;
    }

#pragma unroll
    for (int off = 32; off > 0; off >>= 1)
        m = fmaxf(m, __shfl_xor(m, off, 64));
    if (tx == 0) wm[ty] = m;
    __syncthreads();
    if (tx == 0 && ty == 0) {
        float mm = fmaxf(fmaxf(wm[0], wm[1]), fmaxf(wm[2], wm[3]));
        blockmax[b * NBLK + blockIdx.y * gridDim.x + blockIdx.x] = mm;
    }
}

// Kernel B: one full stage update for a 64x16 tile (4 outputs/thread).
#define TX 64
#define TY 16
#define ZW 66              // z region width  (TX+2)
#define ZH 18              // z region height (TY+2)
#define ZP 67              // padded LDS row stride for z/u (odd -> no bank conflicts)
#define EW 68              // est region width  (TX+4)
#define EH 20              // est region height (TY+4)
#define EP 69              // padded est stride

__global__ __launch_bounds__(256) void stage_kernel(
    const float* __restrict__ est, const float* __restrict__ noisy,
    const float* __restrict__ usig, const float* __restrict__ blockmax,
    const float* __restrict__ filt,  // [8][9] this stage
    const float* __restrict__ wv, const float* __restrict__ bv,
    const float* __restrict__ lamp, const float* __restrict__ gatep,
    float* __restrict__ out)
{
    __shared__ float esh[EH][EP];
    __shared__ float ush[ZH][ZP];
    __shared__ float zsh[NC][ZH][ZP];
    __shared__ float fsh[NC][9];
    __shared__ float wsh[NC], bsh[NC];

    const int tx = threadIdx.x, ty = threadIdx.y;   // block (64,4)
    const int tid = ty * 64 + tx;
    const int x0 = blockIdx.x * TX, y0 = blockIdx.y * TY;
    const int b = blockIdx.z;
    const float* e  = est   + (size_t)b * H * W;
    const float* nz = noisy + (size_t)b * H * W;
    const float* us = usig  + (size_t)b * H * W;

    if (tid < 72) fsh[tid / 9][tid % 9] = filt[tid];
    else if (tid < 80) {
        int c = tid - 72;
        wsh[c] = wv[c] * (2.f * LOG2E);   // tanh in exp2 domain
        bsh[c] = bv[c] * (2.f * LOG2E);
    }

    // per-wave reduction of the 128 per-block maxes for this image
    float m = fmaxf(blockmax[b * NBLK + (tid & 63)],
                    blockmax[b * NBLK + 64 + (tid & 63)]);
#pragma unroll
    for (int off = 32; off > 0; off >>= 1)
        m = fmaxf(m, __shfl_xor(m, off, 64));
    const float dinv = __builtin_amdgcn_rcpf(fmaxf(m, EPS));

    const float lam = lamp[0];
    const float g = __builtin_amdgcn_rcpf(1.f + __builtin_amdgcn_exp2f(-gatep[0] * LOG2E));

    // stage est tile + halo 2 (reflect)
    for (int i = tid; i < EH * EW; i += 256) {
        int ly = i / EW, lx = i % EW;
        esh[ly][lx] = e[refl(y0 + ly - 2, H) * W + refl(x0 + lx - 2, W)];
    }
    // stage u_sigma tile + halo 1 (zero outside)
    for (int i = tid; i < ZH * ZW; i += 256) {
        int ly = i / ZW, lx = i % ZW;
        int gy = y0 + ly - 1, gx = x0 + lx - 1;
        ush[ly][lx] = (gy >= 0 && gy < H && gx >= 0 && gx < W) ? us[gy * W + gx] : 0.f;
    }
    __syncthreads();

    // z over the 66x18 region (zero outside image: zero-pad transpose conv)
    for (int i = tid; i < ZH * ZW; i += 256) {
        int ly = i / ZW, lx = i % ZW;
        int gy = y0 + ly - 1, gx = x0 + lx - 1;
        bool valid = (gy >= 0 && gy < H && gx >= 0 && gx < W);
        float iw = fmaxf(ush[ly][lx] * dinv, EPS);
        float ew[9];
#pragma unroll
        for (int dy = 0; dy < 3; dy++)
#pragma unroll
            for (int dx = 0; dx < 3; dx++)
                ew[dy * 3 + dx] = esh[ly + dy][lx + dx];
#pragma unroll
        for (int c = 0; c < NC; c++) {
            float r = 0.f;
#pragma unroll
            for (int k = 0; k < 9; k++) r += ew[k] * fsh[c][k];
            // tanh(w*r+b) = 1 - 2/(exp2(w'*r+b')+1)
            float a = __builtin_amdgcn_exp2f(r * wsh[c] + bsh[c]);
            float t = 1.f - 2.f * __builtin_amdgcn_rcpf(a + 1.f);
            zsh[c][ly][lx] = valid ? iw * t : 0.f;
        }
    }
    __syncthreads();

    // synthesis conv: channel-outer, vertical rolling window, 4 rows/thread
    const int r0 = ty * 4;
    float acc0 = 0.f, acc1 = 0.f, acc2 = 0.f, acc3 = 0.f;
#pragma unroll
    for (int c = 0; c < NC; c++) {
        float f0 = fsh[c][0], f1 = fsh[c][1], f2 = fsh[c][2];
        float f3 = fsh[c][3], f4 = fsh[c][4], f5 = fsh[c][5];
        float f6 = fsh[c][6], f7 = fsh[c][7], f8 = fsh[c][8];
        float a0 = zsh[c][r0 + 0][tx], a1 = zsh[c][r0 + 0][tx + 1], a2 = zsh[c][r0 + 0][tx + 2];
        float b0 = zsh[c][r0 + 1][tx], b1 = zsh[c][r0 + 1][tx + 1], b2 = zsh[c][r0 + 1][tx + 2];
        float c0 = zsh[c][r0 + 2][tx], c1 = zsh[c][r0 + 2][tx + 1], c2 = zsh[c][r0 + 2][tx + 2];
        acc0 += f0*a0 + f1*a1 + f2*a2 + f3*b0 + f4*b1 + f5*b2 + f6*c0 + f7*c1 + f8*c2;
        float d0 = zsh[c][r0 + 3][tx], d1 = zsh[c][r0 + 3][tx + 1], d2 = zsh[c][r0 + 3][tx + 2];
        acc1 += f0*b0 + f1*b1 + f2*b2 + f3*c0 + f4*c1 + f5*c2 + f6*d0 + f7*d1 + f8*d2;
        float e0 = zsh[c][r0 + 4][tx], e1 = zsh[c][r0 + 4][tx + 1], e2 = zsh[c][r0 + 4][tx + 2];
        acc2 += f0*c0 + f1*c1 + f2*c2 + f3*d0 + f4*d1 + f5*d2 + f6*e0 + f7*e1 + f8*e2;
        float h0 = zsh[c][r0 + 5][tx], h1 = zsh[c][r0 + 5][tx + 1], h2 = zsh[c][r0 + 5][tx + 2];
        acc3 += f0*d0 + f1*d1 + f2*d2 + f3*e0 + f4*e1 + f5*e2 + f6*h0 + f7*h1 + f8*h2;
    }

    float accs[4] = {acc0, acc1, acc2, acc3};
#pragma unroll
    for (int rr = 0; rr < 4; rr++) {
        const int oy = r0 + rr;
        float eo = esh[oy + 2][tx + 2];
        float n0 = nz[(size_t)(y0 + oy) * W + x0 + tx];
        float iwc = fmaxf(ush[oy + 1][tx + 1] * dinv, EPS);
        float fg = (eo - n0) * __builtin_amdgcn_rcpf(eo * eo + EPS);
        float est2 = eo - accs[rr] - lam * iwc * fg;
        float en = est2 + g * (n0 - est2);
        en = fminf(fmaxf(en, EPS), 1.f);
        out[(size_t)b * H * W + (size_t)(y0 + oy) * W + x0 + tx] = en;
    }
}

extern "C" void kernel_launch(void* const* d_in, const int* in_sizes, int n_in,
                              void* d_out, int out_size, void* d_ws, size_t ws_size,
                              hipStream_t stream)
{
    const float* noisy   = (const float*)d_in[0];
    const float* filters = (const float*)d_in[1];  // [7][8][1][3][3]
    const float* wv      = (const float*)d_in[2];  // [7][8]
    const float* bv      = (const float*)d_in[3];  // [7][8]
    const float* lam     = (const float*)d_in[4];  // [7]
    const float* gate    = (const float*)d_in[5];  // [7]
    const float* gauss   = (const float*)d_in[6];  // [25]
    float* out = (float*)d_out;

    char* ws = (char*)d_ws;
    float* ws0      = (float*)ws;                    // 8 MB ping buffer
    float* usig     = (float*)(ws + (8u << 20));     // 8 MB u_sigma
    float* blockmax = (float*)(ws + (16u << 20));    // 128*8 floats, rewritten each stage

    const float* cur = noisy;
    for (int s = 0; s < NS; s++) {
        float* nxt = (s % 2 == 0) ? out : ws0;  // odd stage count -> final lands in out
        gauss_sep_kernel<<<dim3(W / GTX, H / GTY, NB), dim3(64, 4), 0, stream>>>(
            cur, gauss, usig, blockmax);
        stage_kernel<<<dim3(W / TX, H / TY, NB), dim3(64, 4), 0, stream>>>(
            cur, noisy, usig, blockmax,
            filters + s * NC * 9, wv + s * NC, bv + s * NC, lam + s, gate + s, nxt);
        cur = nxt;
    }
}

// Round 4
// 325.208 us; speedup vs baseline: 3.3307x; 1.0171x over previous
//
#include <hip/hip_runtime.h>
#include <hip/hip_bf16.h>

#define EPS 1e-6f
#define H 512
#define W 512
#define NB 8
#define NC 8
#define NS 7
#define LOG2E 1.4426950408889634f

__device__ __forceinline__ int refl(int t, int n) {
    if (t < 0) t = -t;
    if (t >= n) t = 2 * n - 2 - t;
    return t;
}

// ---------------- Kernel A: gaussian-smoothed max only (no u_sigma store) ---------
// block (64,4): each wave = 64 lanes x float4 = 256 cols, 8 output rows.
#define GW 256
#define GR 32
#define NBLK ((W / GW) * (H / GR))   // 32 slots per image

__global__ __launch_bounds__(256) void gauss_max_kernel(
    const float* __restrict__ est, const float* __restrict__ gauss,
    float* __restrict__ blockmax)
{
    const int tx = threadIdx.x, ty = threadIdx.y;
    const int x0 = blockIdx.x * GW;
    const int R  = blockIdx.y * GR + ty * 8;   // first output row of this wave
    const int b  = blockIdx.z;
    const float* e = est + (size_t)b * H * W;
    const int c0 = x0 + tx * 4;

    const float g0 = sqrtf(gauss[0]);
    const float g1 = sqrtf(gauss[6]);
    const float g2 = sqrtf(gauss[12]);

    float4 h0, h1, h2, h3, h4;
    float m = 0.f;

#pragma unroll
    for (int k = 0; k < 12; k++) {
        const float* row = e + refl(R - 2 + k, H) * W;
        float4 v = *(const float4*)&row[c0];
        float em2 = __shfl_up(v.z, 1);
        float em1 = __shfl_up(v.w, 1);
        float ep1 = __shfl_down(v.x, 1);
        float ep2 = __shfl_down(v.y, 1);
        if (tx == 0) {
            if (x0 == 0) { em2 = v.z; em1 = v.y; }
            else         { em2 = row[c0 - 2]; em1 = row[c0 - 1]; }
        }
        if (tx == 63) {
            if (x0 + GW == W) { ep1 = v.z; ep2 = v.y; }
            else              { ep1 = row[c0 + 4]; ep2 = row[c0 + 5]; }
        }
        float4 hc;
        hc.x = g0 * (em2 + v.z) + g1 * (em1 + v.y) + g2 * v.x;
        hc.y = g0 * (em1 + v.w) + g1 * (v.x + v.z) + g2 * v.y;
        hc.z = g0 * (v.x + ep1) + g1 * (v.y + v.w) + g2 * v.z;
        hc.w = g0 * (v.y + ep2) + g1 * (v.z + ep1) + g2 * v.w;
        h0 = h1; h1 = h2; h2 = h3; h3 = h4; h4 = hc;
        if (k >= 4) {
            float ux = g0 * (h0.x + h4.x) + g1 * (h1.x + h3.x) + g2 * h2.x;
            float uy = g0 * (h0.y + h4.y) + g1 * (h1.y + h3.y) + g2 * h2.y;
            float uz = g0 * (h0.z + h4.z) + g1 * (h1.z + h3.z) + g2 * h2.z;
            float uw = g0 * (h0.w + h4.w) + g1 * (h1.w + h3.w) + g2 * h2.w;
            m = fmaxf(m, fmaxf(fmaxf(ux, uy), fmaxf(uz, uw)));
        }
    }

#pragma unroll
    for (int off = 32; off > 0; off >>= 1)
        m = fmaxf(m, __shfl_xor(m, off, 64));
    __shared__ float wm[4];
    if (tx == 0) wm[ty] = m;
    __syncthreads();
    if (tx == 0 && ty == 0) {
        float mm = fmaxf(fmaxf(wm[0], wm[1]), fmaxf(wm[2], wm[3]));
        blockmax[b * NBLK + blockIdx.y * gridDim.x + blockIdx.x] = mm;
    }
}

// ---------------- Kernel B: full stage update, 64x16 tile, u_sigma recomputed -----
#define TX 64
#define TY 16
#define ZW 66              // z/us region width  (TX+2)
#define ZH 18              // z/us region height (TY+2)
#define ZP 67              // padded stride (odd)
#define EW 70              // est region width  (TX+6), halo 3
#define EH 22              // est region height (TY+6)
#define EP 71              // padded est stride
#define HW_ 66             // h-pass region width
#define HH 22              // h-pass region height

__global__ __launch_bounds__(256) void stage_kernel(
    const float* __restrict__ est, const float* __restrict__ noisy,
    const float* __restrict__ blockmax,
    const float* __restrict__ filt,  // [8][9] this stage
    const float* __restrict__ wv, const float* __restrict__ bv,
    const float* __restrict__ lamp, const float* __restrict__ gatep,
    const float* __restrict__ gauss,
    float* __restrict__ out)
{
    __shared__ float esh[EH][EP];
    __shared__ float ush[ZH][ZP];         // holds iw (pre-clamped, 0 outside image)
    __shared__ float zsh[NC][ZH][ZP];     // h-pass buffer overlays this before z
    __shared__ float fsh[NC][9];
    __shared__ float wsh[NC], bsh[NC];

    const int tx = threadIdx.x, ty = threadIdx.y;   // block (64,4)
    const int tid = ty * 64 + tx;
    const int x0 = blockIdx.x * TX, y0 = blockIdx.y * TY;
    const int b = blockIdx.z;
    const float* e  = est   + (size_t)b * H * W;
    const float* nz = noisy + (size_t)b * H * W;

    if (tid < 72) fsh[tid / 9][tid % 9] = filt[tid];
    else if (tid < 80) {
        int c = tid - 72;
        wsh[c] = wv[c] * (2.f * LOG2E);   // tanh in exp2 domain
        bsh[c] = bv[c] * (2.f * LOG2E);
    }

    const float g0 = sqrtf(gauss[0]);
    const float g1 = sqrtf(gauss[6]);
    const float g2 = sqrtf(gauss[12]);

    // per-wave reduction of the 32 per-block maxes for this image
    float m = blockmax[b * NBLK + (tid & 31)];
#pragma unroll
    for (int off = 16; off > 0; off >>= 1)
        m = fmaxf(m, __shfl_xor(m, off, 64));
    const float dinv = __builtin_amdgcn_rcpf(fmaxf(m, EPS));

    const float lam = lamp[0];
    const float g = __builtin_amdgcn_rcpf(1.f + __builtin_amdgcn_exp2f(-gatep[0] * LOG2E));

    // stage est tile + halo 3 (reflect)
    for (int i = tid; i < EH * EW; i += 256) {
        int ly = i / EW, lx = i % EW;
        esh[ly][lx] = e[refl(y0 + ly - 3, H) * W + refl(x0 + lx - 3, W)];
    }
    __syncthreads();

    // gaussian h-pass into overlay buffer (rows y0-3..y0+18, cols x0-1..x0+64)
    float* hb = &zsh[0][0][0];            // HH x ZP region, consumed before z writes
    for (int i = tid; i < HH * HW_; i += 256) {
        int ly = i / HW_, lx = i % HW_;
        hb[ly * ZP + lx] = g0 * (esh[ly][lx] + esh[ly][lx + 4])
                         + g1 * (esh[ly][lx + 1] + esh[ly][lx + 3])
                         + g2 * esh[ly][lx + 2];
    }
    __syncthreads();

    // v-pass -> iw  (zero outside image, pre-clamped, pre-scaled by 1/max)
    for (int i = tid; i < ZH * ZW; i += 256) {
        int ly = i / ZW, lx = i % ZW;
        float us = g0 * (hb[ly * ZP + lx] + hb[(ly + 4) * ZP + lx])
                 + g1 * (hb[(ly + 1) * ZP + lx] + hb[(ly + 3) * ZP + lx])
                 + g2 * hb[(ly + 2) * ZP + lx];
        int gy = y0 + ly - 1, gx = x0 + lx - 1;
        bool valid = (gy >= 0 && gy < H && gx >= 0 && gx < W);
        ush[ly][lx] = valid ? fmaxf(us * dinv, EPS) : 0.f;
    }
    __syncthreads();   // hb consumed; zsh may now be overwritten

    // z over the 66x18 region
    for (int i = tid; i < ZH * ZW; i += 256) {
        int ly = i / ZW, lx = i % ZW;
        float iw = ush[ly][lx];
        float ew[9];
#pragma unroll
        for (int dy = 0; dy < 3; dy++)
#pragma unroll
            for (int dx = 0; dx < 3; dx++)
                ew[dy * 3 + dx] = esh[ly + 1 + dy][lx + 1 + dx];
#pragma unroll
        for (int c = 0; c < NC; c++) {
            float r = 0.f;
#pragma unroll
            for (int k = 0; k < 9; k++) r += ew[k] * fsh[c][k];
            float a = __builtin_amdgcn_exp2f(r * wsh[c] + bsh[c]);
            float t = 1.f - 2.f * __builtin_amdgcn_rcpf(a + 1.f);
            zsh[c][ly][lx] = iw * t;
        }
    }
    __syncthreads();

    // synthesis conv: channel-outer, vertical rolling window, 4 rows/thread
    const int r0 = ty * 4;
    float acc0 = 0.f, acc1 = 0.f, acc2 = 0.f, acc3 = 0.f;
#pragma unroll
    for (int c = 0; c < NC; c++) {
        float f0 = fsh[c][0], f1 = fsh[c][1], f2 = fsh[c][2];
        float f3 = fsh[c][3], f4 = fsh[c][4], f5 = fsh[c][5];
        float f6 = fsh[c][6], f7 = fsh[c][7], f8 = fsh[c][8];
        float a0 = zsh[c][r0 + 0][tx], a1 = zsh[c][r0 + 0][tx + 1], a2 = zsh[c][r0 + 0][tx + 2];
        float b0 = zsh[c][r0 + 1][tx], b1 = zsh[c][r0 + 1][tx + 1], b2 = zsh[c][r0 + 1][tx + 2];
        float c0 = zsh[c][r0 + 2][tx], c1 = zsh[c][r0 + 2][tx + 1], c2 = zsh[c][r0 + 2][tx + 2];
        acc0 += f0*a0 + f1*a1 + f2*a2 + f3*b0 + f4*b1 + f5*b2 + f6*c0 + f7*c1 + f8*c2;
        float d0 = zsh[c][r0 + 3][tx], d1 = zsh[c][r0 + 3][tx + 1], d2 = zsh[c][r0 + 3][tx + 2];
        acc1 += f0*b0 + f1*b1 + f2*b2 + f3*c0 + f4*c1 + f5*c2 + f6*d0 + f7*d1 + f8*d2;
        float e0 = zsh[c][r0 + 4][tx], e1 = zsh[c][r0 + 4][tx + 1], e2 = zsh[c][r0 + 4][tx + 2];
        acc2 += f0*c0 + f1*c1 + f2*c2 + f3*d0 + f4*d1 + f5*d2 + f6*e0 + f7*e1 + f8*e2;
        float h0 = zsh[c][r0 + 5][tx], h1 = zsh[c][r0 + 5][tx + 1], h2 = zsh[c][r0 + 5][tx + 2];
        acc3 += f0*d0 + f1*d1 + f2*d2 + f3*e0 + f4*e1 + f5*e2 + f6*h0 + f7*h1 + f8*h2;
    }

    float accs[4] = {acc0, acc1, acc2, acc3};
#pragma unroll
    for (int rr = 0; rr < 4; rr++) {
        const int oy = r0 + rr;
        float eo = esh[oy + 3][tx + 3];
        float n0 = nz[(size_t)(y0 + oy) * W + x0 + tx];
        float iwc = ush[oy + 1][tx + 1];
        float fg = (eo - n0) * __builtin_amdgcn_rcpf(eo * eo + EPS);
        float est2 = eo - accs[rr] - lam * iwc * fg;
        float en = est2 + g * (n0 - est2);
        en = fminf(fmaxf(en, EPS), 1.f);
        out[(size_t)b * H * W + (size_t)(y0 + oy) * W + x0 + tx] = en;
    }
}

extern "C" void kernel_launch(void* const* d_in, const int* in_sizes, int n_in,
                              void* d_out, int out_size, void* d_ws, size_t ws_size,
                              hipStream_t stream)
{
    const float* noisy   = (const float*)d_in[0];
    const float* filters = (const float*)d_in[1];  // [7][8][1][3][3]
    const float* wv      = (const float*)d_in[2];  // [7][8]
    const float* bv      = (const float*)d_in[3];  // [7][8]
    const float* lam     = (const float*)d_in[4];  // [7]
    const float* gate    = (const float*)d_in[5];  // [7]
    const float* gauss   = (const float*)d_in[6];  // [25]
    float* out = (float*)d_out;

    char* ws = (char*)d_ws;
    float* ws0      = (float*)ws;                    // 8 MB ping buffer
    float* blockmax = (float*)(ws + (8u << 20));     // 32*8 floats, rewritten each stage

    const float* cur = noisy;
    for (int s = 0; s < NS; s++) {
        float* nxt = (s % 2 == 0) ? out : ws0;  // odd stage count -> final lands in out
        gauss_max_kernel<<<dim3(W / GW, H / GR, NB), dim3(64, 4), 0, stream>>>(
            cur, gauss, blockmax);
        stage_kernel<<<dim3(W / TX, H / TY, NB), dim3(64, 4), 0, stream>>>(
            cur, noisy, blockmax,
            filters + s * NC * 9, wv + s * NC, bv + s * NC, lam + s, gate + s, gauss, nxt);
        cur = nxt;
    }
}